// Round 10
// baseline (118.010 us; speedup 1.0000x reference)
//
#include <hip/hip_runtime.h>
#include <cstdint>

// VQ-VAE vector quantizer, MI355X (gfx950). Round 14 -- LDS-resident B.
// Evidence r12/r13: derived counters (MfmaUtil/Occ/VALU) are gfx94x-formula
// fallbacks on gfx950 -- absolutes untrustworthy. Trust dur/FETCH/WRITE only.
// r12 probe decomposition: chase ~140-170us/768 -> L2 load-to-use ~450-530cyc;
// bstream ~15-22us/pass (= BW floor, stream-alone is FINE); score9 (no spill)
// still ~25-40us. => wall = MFMA<->L2-load interleave at 2 waves/SIMD: each
// refill exposes ~450cyc latency vs ~200cyc hideable MFMA -> duty ~40%.
// r14: half-codebook (128KB fp8) LDS-resident per block:
//  - stage ONCE via 16x global_load_lds(16B)/thread + ONE barrier (no convoy);
//  - 8 independent waves x (16-row tile x half codebook) from LDS (lat ~120cyc,
//    covered by depth-2 quarter prefetch; ds_read_b128 : MFMA = 1:2);
//  - halves merged via atomicMin on packed (enc(score)<<32 | idx) -- order-
//    preserving float encode, first-index ties; finalize kernel decodes loss.
// Floors: DS 10.2us, MFMA 8.3, z-HBM(x2) 10.2 -> predict score ~12-18,
// total ~90-97. If total ~115 again: fixed harness overhead ~30us dominates ->
// next round = persistent merged dispatch.

typedef float f32x4 __attribute__((ext_vector_type(4)));
typedef long  l2    __attribute__((ext_vector_type(2)));
typedef _Float16 f16;
typedef f16 f16x8 __attribute__((ext_vector_type(8)));
typedef unsigned long long u64;

#define D_DIM 256
#define K_CODES 1024

__device__ __forceinline__ long pack_fp8x8(float x0, float x1, float x2, float x3,
                                           float x4, float x5, float x6, float x7) {
    int w0 = __builtin_amdgcn_cvt_pk_fp8_f32(x0, x1, 0, false);
    w0     = __builtin_amdgcn_cvt_pk_fp8_f32(x2, x3, w0, true);
    int w1 = __builtin_amdgcn_cvt_pk_fp8_f32(x4, x5, 0, false);
    w1     = __builtin_amdgcn_cvt_pk_fp8_f32(x6, x7, w1, true);
    int2 p = {w0, w1};
    return __builtin_bit_cast(long, p);
}

__device__ __forceinline__ void async_copy16(const void* g, void* l) {
    __builtin_amdgcn_global_load_lds(
        (const __attribute__((address_space(1))) void*)g,
        (__attribute__((address_space(3))) void*)l, 16, 0, 0);
}

// ---- Prep (r5-r13 verified core; + packed init) ----------------------------
__global__ __launch_bounds__(256) void vq_prep(const float* __restrict__ emb,
                                               char* __restrict__ emb8,
                                               float* __restrict__ eTe,
                                               u64* __restrict__ packed,
                                               float* __restrict__ loss_slot) {
    const int tid = threadIdx.x, wave = tid >> 6, lane = tid & 63;
    if (blockIdx.x == 0 && tid == 0) *loss_slot = 0.0f;

    int gtid = blockIdx.x * 256 + tid;
    if (gtid < 32768) packed[gtid] = ~0ULL;     // argmin identity

    if (blockIdx.x < 64) {
        int ch  = blockIdx.x * 256 + tid;     // 16384 chunks
        int sp  = ch >> 10;
        int rem = ch & 1023;
        int ct  = rem >> 8;
        int t   = (rem >> 6) & 3;
        int l   = rem & 63;
        int qq  = l >> 4, mm = l & 15;
        int code = sp * 64 + ct * 16 + mm;
        const float* p = emb + (size_t)code * D_DIM;
        int b0 = t * 64 + qq * 8;
        int b1 = b0 + 32;
        float4 v0 = *(const float4*)(p + b0);
        float4 v1 = *(const float4*)(p + b0 + 4);
        float4 v2 = *(const float4*)(p + b1);
        float4 v3 = *(const float4*)(p + b1 + 4);
        l2 out;
        out.x = pack_fp8x8(v0.x * 1024.f, v0.y * 1024.f, v0.z * 1024.f, v0.w * 1024.f,
                           v1.x * 1024.f, v1.y * 1024.f, v1.z * 1024.f, v1.w * 1024.f);
        out.y = pack_fp8x8(v2.x * 1024.f, v2.y * 1024.f, v2.z * 1024.f, v2.w * 1024.f,
                           v3.x * 1024.f, v3.y * 1024.f, v3.z * 1024.f, v3.w * 1024.f);
        *(l2*)(emb8 + (size_t)ch * 16) = out;
    }

    // eTe: one wave per code, 4 codes per block, pre-scaled by 1024.
    int code = blockIdx.x * 4 + wave;
    float4 v = ((const float4*)(emb + (size_t)code * D_DIM))[lane];
    float s = v.x * v.x + v.y * v.y + v.z * v.z + v.w * v.w;
    #pragma unroll
    for (int off = 32; off >= 1; off >>= 1) s += __shfl_down(s, off);
    if (lane == 0) eTe[code] = 1024.0f * s;
}

// ---- Score kernel: LDS-resident half codebook ------------------------------
__device__ __forceinline__ void loadQL(l2 (&Q)[4], const char* sB,
                                       int sl, int t, int lane) {
    const l2* p = (const l2*)sB + sl * 1024 + t * 64 + lane;   // ds_read_b128 x4
    Q[0] = p[0];
    Q[1] = p[256];
    Q[2] = p[512];
    Q[3] = p[768];
}

__device__ __forceinline__ void mfmaQ(f32x4 (&acc)[4], const l2 (&Q)[4],
                                      long a0, long a1) {
    #pragma unroll
    for (int ct = 0; ct < 4; ct++) {
        acc[ct] = __builtin_amdgcn_mfma_f32_16x16x32_fp8_fp8(a0, Q[ct].x, acc[ct], 0, 0, 0);
        acc[ct] = __builtin_amdgcn_mfma_f32_16x16x32_fp8_fp8(a1, Q[ct].y, acc[ct], 0, 0, 0);
    }
}

// Block = 512 thr: stages half codebook h (128KB) to LDS once; 8 independent
// waves each score one 16-row tile against the half. One barrier total.
// Merge across halves: atomicMin on packed (enc(score)<<32 | idx).
__global__ __launch_bounds__(512, 2) void vq_score10(const float* __restrict__ z,
                                                     const char* __restrict__ emb8,
                                                     const float* __restrict__ eTe,
                                                     u64* __restrict__ packed,
                                                     float* __restrict__ loss_slot,
                                                     float loss_scale) {
    __shared__ __align__(16) char sB[131072];   // 128 KB half codebook
    __shared__ float s_ete[512];                // 2 KB
    __shared__ float s_red[8];

    const int tid  = threadIdx.x;
    const int w    = tid >> 6;                  // 0..7 = row tile within group
    const int lane = tid & 63;
    const int m    = lane & 15;
    const int q    = lane >> 4;
    const int h    = blockIdx.x & 1;            // codebook half
    const int g    = blockIdx.x >> 1;           // row group 0..255
    const size_t row0 = ((size_t)g * 8 + w) * 16;

    // Stage half codebook (async; drained by the barrier below).
    {
        const char* src = emb8 + (size_t)h * 131072;
        #pragma unroll
        for (int i = 0; i < 16; i++) {
            int c = i * 512 + tid;
            async_copy16(src + (size_t)c * 16, sB + (size_t)c * 16);
        }
    }
    s_ete[tid & 511] = eTe[h * 512 + (tid & 511)];

    // A fragments (verified r5-r13 layout): lane (q,m) = row m, k-dims
    // [s*32+q*8,+8) per k-step s. Loads overlap the async staging.
    long A8[8];
    float zsq = 0.f;
    {
        const float* zr = z + (row0 + m) * D_DIM;
        #pragma unroll
        for (int s = 0; s < 8; s++) {
            const float* p = zr + s * 32 + q * 8;
            float4 v0 = *(const float4*)p;
            float4 v1 = *(const float4*)(p + 4);
            zsq += v0.x * v0.x + v0.y * v0.y + v0.z * v0.z + v0.w * v0.w
                 + v1.x * v1.x + v1.y * v1.y + v1.z * v1.z + v1.w * v1.w;
            A8[s] = pack_fp8x8(v0.x, v0.y, v0.z, v0.w, v1.x, v1.y, v1.z, v1.w);
        }
    }
    __syncthreads();                            // sB + s_ete ready

    l2 Qa[4], Qb[4];
    loadQL(Qa, sB, 0, 0, lane);
    loadQL(Qb, sB, 0, 1, lane);

    float best[4];
    int   bidx[4];
    #pragma unroll
    for (int r = 0; r < 4; r++) { best[r] = __builtin_inff(); bidx[r] = 0; }

    // 8 slices from LDS; zero barriers; quarter-pipeline (depth 2 >> 120cyc).
    #pragma unroll 1
    for (int sl = 0; sl < 8; ++sl) {
        float ete[4];
        #pragma unroll
        for (int ct = 0; ct < 4; ct++) ete[ct] = s_ete[sl * 64 + ct * 16 + m];

        f32x4 acc[4];
        #pragma unroll
        for (int ct = 0; ct < 4; ct++) acc[ct] = (f32x4){0.f, 0.f, 0.f, 0.f};

        __builtin_amdgcn_s_setprio(1);
        mfmaQ(acc, Qa, A8[0], A8[1]);
        __builtin_amdgcn_s_setprio(0);
        loadQL(Qa, sB, sl, 2, lane);
        __builtin_amdgcn_s_setprio(1);
        mfmaQ(acc, Qb, A8[2], A8[3]);
        __builtin_amdgcn_s_setprio(0);
        loadQL(Qb, sB, sl, 3, lane);
        __builtin_amdgcn_s_setprio(1);
        mfmaQ(acc, Qa, A8[4], A8[5]);
        __builtin_amdgcn_s_setprio(0);
        if (sl + 1 < 8) loadQL(Qa, sB, sl + 1, 0, lane);
        __builtin_amdgcn_s_setprio(1);
        mfmaQ(acc, Qb, A8[6], A8[7]);
        __builtin_amdgcn_s_setprio(0);
        if (sl + 1 < 8) loadQL(Qb, sB, sl + 1, 1, lane);

        // Ascending code order + strict < -> first-index argmin within half.
        #pragma unroll
        for (int ct = 0; ct < 4; ct++) {
            const int code = (h * 8 + sl) * 64 + ct * 16 + m;
            #pragma unroll
            for (int r = 0; r < 4; r++) {
                float sc = fmaf(-2.0f, acc[ct][r], ete[ct]);
                if (sc < best[r]) { best[r] = sc; bidx[r] = code; }
            }
        }
    }

    // Cross-lane argmin per q-group; then pack + atomicMin merge.
    #pragma unroll
    for (int r = 0; r < 4; r++) {
        float b  = best[r];
        int   bi = bidx[r];
        #pragma unroll
        for (int off = 8; off >= 1; off >>= 1) {
            float ob = __shfl_xor(b, off);
            int   oi = __shfl_xor(bi, off);
            if (ob < b || (ob == b && oi < bi)) { b = ob; bi = oi; }
        }
        if (m == 0) {
            // order-preserving float encode: min(pk) == (min score, min idx)
            unsigned int u = __float_as_uint(b);
            u = (u & 0x80000000u) ? ~u : (u | 0x80000000u);
            u64 pk = ((u64)u << 32) | (unsigned int)bi;
            atomicMin(&packed[row0 + q * 4 + r], pk);
        }
    }

    // zsq part of the loss: each row's zsq counted once (half 0 only).
    #pragma unroll
    for (int off = 32; off >= 1; off >>= 1) zsq += __shfl_down(zsq, off);
    if (lane == 0) s_red[w] = zsq;
    __syncthreads();
    if (tid == 0 && h == 0) {
        float t = 0.f;
        #pragma unroll
        for (int i = 0; i < 8; i++) t += s_red[i];
        atomicAdd(loss_slot, t * loss_scale);
    }
}

// ---- Gather: out[row] = emb[idx]; idx = low 32 bits of packed. -------------
__global__ __launch_bounds__(256) void vq_gather(const float* __restrict__ emb,
                                                 const u64* __restrict__ packed,
                                                 float* __restrict__ out,
                                                 int nrows) {
    const int lane = threadIdx.x & 63;
    const int gw   = (blockIdx.x * 256 + threadIdx.x) >> 6;
    const int nw   = (gridDim.x * 256) >> 6;
    for (int row = gw; row < nrows; row += nw) {
        int bi = (int)(packed[row] & 0xFFFFFFFFull);
        float4 ev = *((const float4*)(emb + (size_t)bi * D_DIM) + lane);
        *((float4*)(out + (size_t)row * D_DIM) + lane) = ev;
    }
}

// ---- Finalize: loss += sum(dec(score))/1024 * scale. -----------------------
__global__ __launch_bounds__(512) void vq_finalize(const u64* __restrict__ packed,
                                                   float* __restrict__ loss_slot,
                                                   float loss_scale, int nrows) {
    __shared__ float s_red[8];
    int gtid = blockIdx.x * 512 + threadIdx.x;
    float v = 0.f;
    if (gtid < nrows) {
        unsigned int hi = (unsigned int)(packed[gtid] >> 32);
        unsigned int u  = (hi & 0x80000000u) ? (hi ^ 0x80000000u) : ~hi;
        v = __uint_as_float(u) * (1.0f / 1024.0f);
    }
    #pragma unroll
    for (int off = 32; off >= 1; off >>= 1) v += __shfl_down(v, off);
    if ((threadIdx.x & 63) == 0) s_red[threadIdx.x >> 6] = v;
    __syncthreads();
    if (threadIdx.x == 0) {
        float t = 0.f;
        #pragma unroll
        for (int i = 0; i < 8; i++) t += s_red[i];
        atomicAdd(loss_slot, t * loss_scale);
    }
}

// ---- Fallback (round-2 structure, verified) — only if ws too small. --------
__global__ __launch_bounds__(256) void vq_prep_fb(const float* __restrict__ emb,
                                                  float* __restrict__ eTe,
                                                  float* __restrict__ loss_slot) {
    if (blockIdx.x == 0 && threadIdx.x == 0) *loss_slot = 0.0f;
    if (!eTe) return;
    int gtid = blockIdx.x * 256 + threadIdx.x;
    int code = gtid >> 6;
    int lane = threadIdx.x & 63;
    if (code >= K_CODES) return;
    float4 v = ((const float4*)(emb + (size_t)code * D_DIM))[lane];
    float s = v.x * v.x + v.y * v.y + v.z * v.z + v.w * v.w;
    #pragma unroll
    for (int off = 32; off >= 1; off >>= 1) s += __shfl_down(s, off);
    if (lane == 0) eTe[code] = s;
}

__global__ __launch_bounds__(128) void vq_main_fb(const float* __restrict__ z,
                                                  const float* __restrict__ emb,
                                                  const float* __restrict__ eTe_g,
                                                  float* __restrict__ out,
                                                  float* __restrict__ loss_slot,
                                                  float loss_scale) {
    __shared__ __align__(16) f16 sE[128 * D_DIM];
    __shared__ float s_ete[128];
    __shared__ int   s_idx2[128];
    __shared__ float s_red2[2];

    const int tid  = threadIdx.x;
    const int wave = tid >> 6;
    const int lane = tid & 63;
    const int m    = lane & 15;
    const int q    = lane >> 4;
    const size_t row0 = (size_t)blockIdx.x * 128 + (size_t)wave * 64;

    f16x8 A[4][8];
    #pragma unroll
    for (int st = 0; st < 4; st++) {
        const float* zr = z + (row0 + st * 16 + m) * D_DIM;
        #pragma unroll
        for (int s = 0; s < 8; s++) {
            const float* p = zr + s * 32 + q * 8;
            float4 v0 = *(const float4*)p;
            float4 v1 = *(const float4*)(p + 4);
            f16x8 a = {(f16)v0.x, (f16)v0.y, (f16)v0.z, (f16)v0.w,
                       (f16)v1.x, (f16)v1.y, (f16)v1.z, (f16)v1.w};
            A[st][s] = a;
        }
    }
    float best[4][4]; int bidx[4][4];
    #pragma unroll
    for (int st = 0; st < 4; st++)
        #pragma unroll
        for (int r = 0; r < 4; r++) { best[st][r] = __builtin_inff(); bidx[st][r] = 0; }

    const f16x8* sE8 = (const f16x8*)sE;
    #pragma unroll 1
    for (int sp = 0; sp < 8; sp++) {
        __syncthreads();
        if (eTe_g) s_ete[tid] = 1024.0f * eTe_g[sp * 128 + tid];
        else {
            const float* p = emb + (size_t)(sp * 128 + tid) * D_DIM;
            float ss = 0.f;
            for (int j = 0; j < D_DIM / 4; j++) {
                float4 v = ((const float4*)p)[j];
                ss += v.x * v.x + v.y * v.y + v.z * v.z + v.w * v.w;
            }
            s_ete[tid] = 1024.0f * ss;
        }
        const float* ebase = emb + (size_t)sp * 128 * D_DIM;
        #pragma unroll 4
        for (int it = 0; it < 32; it++) {
            int ch = it * 128 + tid;
            int cc = ((ch >> 9) << 4) | (ch & 15);
            int gg = (ch >> 4) & 31;
            const float* p = ebase + cc * D_DIM + gg * 8;
            float4 v0 = *(const float4*)p;
            float4 v1 = *(const float4*)(p + 4);
            f16x8 h = {(f16)(v0.x * 1024.f), (f16)(v0.y * 1024.f),
                       (f16)(v0.z * 1024.f), (f16)(v0.w * 1024.f),
                       (f16)(v1.x * 1024.f), (f16)(v1.y * 1024.f),
                       (f16)(v1.z * 1024.f), (f16)(v1.w * 1024.f)};
            *(f16x8*)(sE + (size_t)ch * 8) = h;
        }
        __syncthreads();
        for (int ct = 0; ct < 8; ct++) {
            f32x4 acc[4];
            #pragma unroll
            for (int st = 0; st < 4; st++) acc[st] = (f32x4){0.f, 0.f, 0.f, 0.f};
            #pragma unroll
            for (int s = 0; s < 8; s++) {
                f16x8 bh = sE8[ct * 512 + s * 64 + lane];
                #pragma unroll
                for (int st = 0; st < 4; st++)
                    acc[st] = __builtin_amdgcn_mfma_f32_16x16x32_f16(A[st][s], bh, acc[st], 0, 0, 0);
            }
            int codeL = ct * 16 + m;
            float ete = s_ete[codeL];
            int code  = sp * 128 + codeL;
            #pragma unroll
            for (int st = 0; st < 4; st++)
                #pragma unroll
                for (int r = 0; r < 4; r++) {
                    float sc = fmaf(-2.0f, acc[st][r], ete);
                    if (sc < best[st][r]) { best[st][r] = sc; bidx[st][r] = code; }
                }
        }
    }
    #pragma unroll
    for (int st = 0; st < 4; st++)
        #pragma unroll
        for (int r = 0; r < 4; r++) {
            float b = best[st][r]; int bi = bidx[st][r];
            #pragma unroll
            for (int off = 8; off >= 1; off >>= 1) {
                float ob = __shfl_xor(b, off);
                int   oi = __shfl_xor(bi, off);
                if (ob < b || (ob == b && oi < bi)) { b = ob; bi = oi; }
            }
            if (m == 0) s_idx2[wave * 64 + st * 16 + q * 4 + r] = bi;
        }
    __syncthreads();
    float lsum = 0.f;
    #pragma unroll
    for (int st = 0; st < 4; st++) {
        int rl = wave * 64 + st * 16 + m;
        int idxv = s_idx2[rl];
        const float* er = emb + (size_t)idxv * D_DIM;
        float* orow = out + ((size_t)blockIdx.x * 128 + rl) * D_DIM;
        #pragma unroll
        for (int s = 0; s < 8; s++) {
            int dd = s * 32 + q * 8;
            float4 e0 = *(const float4*)(er + dd);
            float4 e1 = *(const float4*)(er + dd + 4);
            *(float4*)(orow + dd)     = e0;
            *(float4*)(orow + dd + 4) = e1;
            f16x8 a = A[st][s];
            float d0 = e0.x - (float)a[0], d1 = e0.y - (float)a[1];
            float d2 = e0.z - (float)a[2], d3 = e0.w - (float)a[3];
            float d4 = e1.x - (float)a[4], d5 = e1.y - (float)a[5];
            float d6 = e1.z - (float)a[6], d7 = e1.w - (float)a[7];
            lsum += d0*d0 + d1*d1 + d2*d2 + d3*d3 + d4*d4 + d5*d5 + d6*d6 + d7*d7;
        }
    }
    #pragma unroll
    for (int off = 32; off >= 1; off >>= 1) lsum += __shfl_down(lsum, off);
    if (lane == 0) s_red2[wave] = lsum;
    __syncthreads();
    if (tid == 0) atomicAdd(loss_slot, (s_red2[0] + s_red2[1]) * loss_scale);
}

extern "C" void kernel_launch(void* const* d_in, const int* in_sizes, int n_in,
                              void* d_out, int out_size, void* d_ws, size_t ws_size,
                              hipStream_t stream) {
    const float* z   = (const float*)d_in[0];
    const float* emb = (const float*)d_in[1];
    float* out = (float*)d_out;
    const int NROWS = in_sizes[0] / D_DIM;                  // 32768
    float* loss_slot = out + (size_t)in_sizes[0];
    float loss_scale = 1.25f / (float)in_sizes[0];

    const size_t emb8_bytes = (size_t)K_CODES * D_DIM;      // 256 KB
    const size_t ete_bytes  = K_CODES * sizeof(float);      // 4 KB
    const size_t pk_bytes   = (size_t)NROWS * sizeof(u64);  // 256 KB
    const size_t need = emb8_bytes + ete_bytes + pk_bytes;

    if (ws_size >= need) {
        char*  emb8 = (char*)d_ws;
        float* eTe  = (float*)((char*)d_ws + emb8_bytes);
        u64*   pk   = (u64*)((char*)d_ws + emb8_bytes + ete_bytes);
        vq_prep<<<256, 256, 0, stream>>>(emb, emb8, eTe, pk, loss_slot);
        vq_score10<<<512, 512, 0, stream>>>(z, emb8, eTe, pk, loss_slot, loss_scale);
        vq_gather<<<2048, 256, 0, stream>>>(emb, pk, out, NROWS);
        vq_finalize<<<64, 512, 0, stream>>>(pk, loss_slot, loss_scale, NROWS);
    } else {
        float* eTe = (ws_size >= ete_bytes) ? (float*)d_ws : nullptr;
        vq_prep_fb<<<K_CODES / 4, 256, 0, stream>>>(emb, eTe, loss_slot);
        vq_main_fb<<<NROWS / 128, 128, 0, stream>>>(z, emb, eTe, out, loss_slot, loss_scale);
    }
}

// Round 12
// 105.590 us; speedup vs baseline: 1.1176x; 1.1176x over previous
//
#include <hip/hip_runtime.h>
#include <cstdint>

// VQ-VAE vector quantizer, MI355X (gfx950). Round 15 RESUBMIT (r11 bench was
// an infra failure -- container acquisition; kernel never ran).
// Accounting across r10-r14: fixed harness component ~50-65us (268MB ws
// re-poison fill = 42.6us at 6.3TB/s + graph gaps); our pipeline ~55-68us
// spread over 4 dispatches with duplicated traffic (packed 256KB w+2r, out
// written by a 4th kernel). r14 proved LDS-resident scoring passes and is
// <42us. r15 fuses score+merge+gather+loss into ONE kernel:
//  - block 512thr, grid 256 (1 block/CU, 135KB LDS): stage half0 (128KB,
//    async_copy16 x16/thr), score 8 slices from LDS (quarter-pipelined,
//    verified r14); barrier; restage half1; score -> full-codebook argmin
//    stays IN-LANE (ascending code order + strict < = first-index).
//  - butterfly once/wave, gather emb rows (L2), write out, loss -- r7-verified
//    epilogue. No atomicMin/packed/finalize/gather dispatches.
// Per-CU floors: DS 10.2us, MFMA 8.3 (overlap), z 5.3, out 5.3, stage 2.4
// -> main ~18-25us; 2 dispatches total. Predict total ~85-105.
// If total ~113-120 AGAIN with a ~28us-floor 2-dispatch pipeline: the floor
// is the harness's fixed overhead -- declare and stop next round.

typedef float f32x4 __attribute__((ext_vector_type(4)));
typedef long  l2    __attribute__((ext_vector_type(2)));
typedef _Float16 f16;
typedef f16 f16x8 __attribute__((ext_vector_type(8)));

#define D_DIM 256
#define K_CODES 1024

__device__ __forceinline__ long pack_fp8x8(float x0, float x1, float x2, float x3,
                                           float x4, float x5, float x6, float x7) {
    int w0 = __builtin_amdgcn_cvt_pk_fp8_f32(x0, x1, 0, false);
    w0     = __builtin_amdgcn_cvt_pk_fp8_f32(x2, x3, w0, true);
    int w1 = __builtin_amdgcn_cvt_pk_fp8_f32(x4, x5, 0, false);
    w1     = __builtin_amdgcn_cvt_pk_fp8_f32(x6, x7, w1, true);
    int2 p = {w0, w1};
    return __builtin_bit_cast(long, p);
}

__device__ __forceinline__ void async_copy16(const void* g, void* l) {
    __builtin_amdgcn_global_load_lds(
        (const __attribute__((address_space(1))) void*)g,
        (__attribute__((address_space(3))) void*)l, 16, 0, 0);
}

// ---- Prep (verified r5-r14, unchanged): emb -> fp8 (x1024) slice-linear;
// eTe = 1024*||e||^2. grid 256 x 256.
__global__ __launch_bounds__(256) void vq_prep(const float* __restrict__ emb,
                                               char* __restrict__ emb8,
                                               float* __restrict__ eTe,
                                               float* __restrict__ loss_slot) {
    const int tid = threadIdx.x, wave = tid >> 6, lane = tid & 63;
    if (blockIdx.x == 0 && tid == 0) *loss_slot = 0.0f;

    if (blockIdx.x < 64) {
        int ch  = blockIdx.x * 256 + tid;     // 16384 chunks
        int sp  = ch >> 10;
        int rem = ch & 1023;
        int ct  = rem >> 8;
        int t   = (rem >> 6) & 3;
        int l   = rem & 63;
        int qq  = l >> 4, mm = l & 15;
        int code = sp * 64 + ct * 16 + mm;
        const float* p = emb + (size_t)code * D_DIM;
        int b0 = t * 64 + qq * 8;
        int b1 = b0 + 32;
        float4 v0 = *(const float4*)(p + b0);
        float4 v1 = *(const float4*)(p + b0 + 4);
        float4 v2 = *(const float4*)(p + b1);
        float4 v3 = *(const float4*)(p + b1 + 4);
        l2 out;
        out.x = pack_fp8x8(v0.x * 1024.f, v0.y * 1024.f, v0.z * 1024.f, v0.w * 1024.f,
                           v1.x * 1024.f, v1.y * 1024.f, v1.z * 1024.f, v1.w * 1024.f);
        out.y = pack_fp8x8(v2.x * 1024.f, v2.y * 1024.f, v2.z * 1024.f, v2.w * 1024.f,
                           v3.x * 1024.f, v3.y * 1024.f, v3.z * 1024.f, v3.w * 1024.f);
        *(l2*)(emb8 + (size_t)ch * 16) = out;
    }

    // eTe: one wave per code, 4 codes per block, pre-scaled by 1024.
    int code = blockIdx.x * 4 + wave;
    float4 v = ((const float4*)(emb + (size_t)code * D_DIM))[lane];
    float s = v.x * v.x + v.y * v.y + v.z * v.z + v.w * v.w;
    #pragma unroll
    for (int off = 32; off >= 1; off >>= 1) s += __shfl_down(s, off);
    if (lane == 0) eTe[code] = 1024.0f * s;
}

// ---- Fused main ------------------------------------------------------------
__device__ __forceinline__ void loadQL(l2 (&Q)[4], const char* sB,
                                       int sl, int t, int lane) {
    const l2* p = (const l2*)sB + sl * 1024 + t * 64 + lane;   // ds_read_b128 x4
    Q[0] = p[0];
    Q[1] = p[256];
    Q[2] = p[512];
    Q[3] = p[768];
}

__device__ __forceinline__ void mfmaQ(f32x4 (&acc)[4], const l2 (&Q)[4],
                                      long a0, long a1) {
    #pragma unroll
    for (int ct = 0; ct < 4; ct++) {
        acc[ct] = __builtin_amdgcn_mfma_f32_16x16x32_fp8_fp8(a0, Q[ct].x, acc[ct], 0, 0, 0);
        acc[ct] = __builtin_amdgcn_mfma_f32_16x16x32_fp8_fp8(a1, Q[ct].y, acc[ct], 0, 0, 0);
    }
}

// Score 8 LDS-resident slices (one half); codeH = half*512. Verified r14 loop.
__device__ __forceinline__ void scoreHalf(const char* sB, const float* s_ete,
                                          int codeH, const long (&A8)[8],
                                          int m, int lane,
                                          float (&best)[4], int (&bidx)[4]) {
    l2 Qa[4], Qb[4];
    loadQL(Qa, sB, 0, 0, lane);
    loadQL(Qb, sB, 0, 1, lane);

    #pragma unroll 1
    for (int sl = 0; sl < 8; ++sl) {
        float ete[4];
        #pragma unroll
        for (int ct = 0; ct < 4; ct++) ete[ct] = s_ete[codeH + sl * 64 + ct * 16 + m];

        f32x4 acc[4];
        #pragma unroll
        for (int ct = 0; ct < 4; ct++) acc[ct] = (f32x4){0.f, 0.f, 0.f, 0.f};

        __builtin_amdgcn_s_setprio(1);
        mfmaQ(acc, Qa, A8[0], A8[1]);
        __builtin_amdgcn_s_setprio(0);
        loadQL(Qa, sB, sl, 2, lane);
        __builtin_amdgcn_s_setprio(1);
        mfmaQ(acc, Qb, A8[2], A8[3]);
        __builtin_amdgcn_s_setprio(0);
        loadQL(Qb, sB, sl, 3, lane);
        __builtin_amdgcn_s_setprio(1);
        mfmaQ(acc, Qa, A8[4], A8[5]);
        __builtin_amdgcn_s_setprio(0);
        if (sl + 1 < 8) loadQL(Qa, sB, sl + 1, 0, lane);
        __builtin_amdgcn_s_setprio(1);
        mfmaQ(acc, Qb, A8[6], A8[7]);
        __builtin_amdgcn_s_setprio(0);
        if (sl + 1 < 8) loadQL(Qb, sB, sl + 1, 1, lane);

        // Ascending code order + strict < -> first-index argmin.
        #pragma unroll
        for (int ct = 0; ct < 4; ct++) {
            const int code = codeH + sl * 64 + ct * 16 + m;
            #pragma unroll
            for (int r = 0; r < 4; r++) {
                float sc = fmaf(-2.0f, acc[ct][r], ete[ct]);
                if (sc < best[r]) { best[r] = sc; bidx[r] = code; }
            }
        }
    }
}

// Block = 512 thr (8 waves x 16 rows = 128 rows), grid 256 (1 block/CU).
// Stage half0 -> score -> restage half1 -> score; argmin closes in-lane;
// epilogue gathers + writes + loss (r7-verified).
__global__ __launch_bounds__(512, 2) void vq_main7(const float* __restrict__ z,
                                                   const char* __restrict__ emb8,
                                                   const float* __restrict__ eTe,
                                                   const float* __restrict__ emb,
                                                   float* __restrict__ out,
                                                   float* __restrict__ loss_slot,
                                                   float loss_scale) {
    __shared__ __align__(16) char sB[131072];   // half codebook, reused
    __shared__ float s_ete[K_CODES];            // 4 KB, both halves
    __shared__ float s_red[8];

    const int tid  = threadIdx.x;
    const int w    = tid >> 6;
    const int lane = tid & 63;
    const int m    = lane & 15;
    const int q    = lane >> 4;
    const size_t row0 = ((size_t)blockIdx.x * 8 + w) * 16;

    // Stage half 0 (async; drained by first barrier).
    #pragma unroll
    for (int i = 0; i < 16; i++) {
        int c = i * 512 + tid;
        async_copy16(emb8 + (size_t)c * 16, sB + (size_t)c * 16);
    }
    s_ete[tid]       = eTe[tid];
    s_ete[tid + 512] = eTe[tid + 512];

    // A fragments (verified r5-r14 layout): lane (q,m) = row m, k-dims
    // [s*32+q*8,+8) per k-step s. Overlaps the async staging.
    long A8[8];
    float zsq = 0.f;
    {
        const float* zr = z + (row0 + m) * D_DIM;
        #pragma unroll
        for (int s = 0; s < 8; s++) {
            const float* p = zr + s * 32 + q * 8;
            float4 v0 = *(const float4*)p;
            float4 v1 = *(const float4*)(p + 4);
            zsq += v0.x * v0.x + v0.y * v0.y + v0.z * v0.z + v0.w * v0.w
                 + v1.x * v1.x + v1.y * v1.y + v1.z * v1.z + v1.w * v1.w;
            A8[s] = pack_fp8x8(v0.x, v0.y, v0.z, v0.w, v1.x, v1.y, v1.z, v1.w);
        }
    }
    __syncthreads();                            // half0 + s_ete ready

    float best[4];
    int   bidx[4];
    #pragma unroll
    for (int r = 0; r < 4; r++) { best[r] = __builtin_inff(); bidx[r] = 0; }

    scoreHalf(sB, s_ete, 0, A8, m, lane, best, bidx);

    __syncthreads();                            // all reads of half0 done

    // Restage half 1 into the same buffer.
    #pragma unroll
    for (int i = 0; i < 16; i++) {
        int c = i * 512 + tid;
        async_copy16(emb8 + 131072 + (size_t)c * 16, sB + (size_t)c * 16);
    }
    __syncthreads();                            // half1 staged (vmcnt drained)

    scoreHalf(sB, s_ete, 512, A8, m, lane, best, bidx);

    // Cross-lane argmin per q-group (tie -> smaller index = first index).
    #pragma unroll
    for (int r = 0; r < 4; r++) {
        float b  = best[r];
        int   bi = bidx[r];
        #pragma unroll
        for (int off = 8; off >= 1; off >>= 1) {
            float ob = __shfl_xor(b, off);
            int   oi = __shfl_xor(bi, off);
            if (ob < b || (ob == b && oi < bi)) { b = ob; bi = oi; }
        }
        best[r] = b; bidx[r] = bi;              // uniform within q-group
    }

    // Epilogue (r7-verified): row (qq*4+r) idx from lane qq*16; gather emb row
    // (L2-hot, 1KB coalesced); write out row (1KB coalesced).
    float lsum = 0.f;
    float* orow0 = out + row0 * D_DIM + (size_t)lane * 4;
    #pragma unroll
    for (int row = 0; row < 16; row++) {
        const int r  = row & 3;
        const int qq = row >> 2;
        int   bi = __shfl(bidx[r], qq * 16);
        float b  = __shfl(best[r], qq * 16);
        lsum += b;                               // uniform across lanes
        float4 ev = *(const float4*)(emb + (size_t)bi * D_DIM + lane * 4);
        *(float4*)(orow0 + (size_t)row * D_DIM) = ev;
    }

    // loss: sum(z^2) over wave's rows + sum(best)/1024; one atomic per block.
    #pragma unroll
    for (int off = 32; off >= 1; off >>= 1) zsq += __shfl_down(zsq, off);
    if (lane == 0) s_red[w] = zsq + lsum * (1.0f / 1024.0f);
    __syncthreads();
    if (tid == 0) {
        float t = 0.f;
        #pragma unroll
        for (int i = 0; i < 8; i++) t += s_red[i];
        atomicAdd(loss_slot, t * loss_scale);
    }
}

// ---- Fallback (round-2 structure, verified) — only if ws too small. --------
__global__ __launch_bounds__(256) void vq_prep_fb(const float* __restrict__ emb,
                                                  float* __restrict__ eTe,
                                                  float* __restrict__ loss_slot) {
    if (blockIdx.x == 0 && threadIdx.x == 0) *loss_slot = 0.0f;
    if (!eTe) return;
    int gtid = blockIdx.x * 256 + threadIdx.x;
    int code = gtid >> 6;
    int lane = threadIdx.x & 63;
    if (code >= K_CODES) return;
    float4 v = ((const float4*)(emb + (size_t)code * D_DIM))[lane];
    float s = v.x * v.x + v.y * v.y + v.z * v.z + v.w * v.w;
    #pragma unroll
    for (int off = 32; off >= 1; off >>= 1) s += __shfl_down(s, off);
    if (lane == 0) eTe[code] = s;
}

__global__ __launch_bounds__(128) void vq_main_fb(const float* __restrict__ z,
                                                  const float* __restrict__ emb,
                                                  const float* __restrict__ eTe_g,
                                                  float* __restrict__ out,
                                                  float* __restrict__ loss_slot,
                                                  float loss_scale) {
    __shared__ __align__(16) f16 sE[128 * D_DIM];
    __shared__ float s_ete[128];
    __shared__ int   s_idx2[128];
    __shared__ float s_red2[2];

    const int tid  = threadIdx.x;
    const int wave = tid >> 6;
    const int lane = tid & 63;
    const int m    = lane & 15;
    const int q    = lane >> 4;
    const size_t row0 = (size_t)blockIdx.x * 128 + (size_t)wave * 64;

    f16x8 A[4][8];
    #pragma unroll
    for (int st = 0; st < 4; st++) {
        const float* zr = z + (row0 + st * 16 + m) * D_DIM;
        #pragma unroll
        for (int s = 0; s < 8; s++) {
            const float* p = zr + s * 32 + q * 8;
            float4 v0 = *(const float4*)p;
            float4 v1 = *(const float4*)(p + 4);
            f16x8 a = {(f16)v0.x, (f16)v0.y, (f16)v0.z, (f16)v0.w,
                       (f16)v1.x, (f16)v1.y, (f16)v1.z, (f16)v1.w};
            A[st][s] = a;
        }
    }
    float best[4][4]; int bidx[4][4];
    #pragma unroll
    for (int st = 0; st < 4; st++)
        #pragma unroll
        for (int r = 0; r < 4; r++) { best[st][r] = __builtin_inff(); bidx[st][r] = 0; }

    const f16x8* sE8 = (const f16x8*)sE;
    #pragma unroll 1
    for (int sp = 0; sp < 8; sp++) {
        __syncthreads();
        if (eTe_g) s_ete[tid] = 1024.0f * eTe_g[sp * 128 + tid];
        else {
            const float* p = emb + (size_t)(sp * 128 + tid) * D_DIM;
            float ss = 0.f;
            for (int j = 0; j < D_DIM / 4; j++) {
                float4 v = ((const float4*)p)[j];
                ss += v.x * v.x + v.y * v.y + v.z * v.z + v.w * v.w;
            }
            s_ete[tid] = 1024.0f * ss;
        }
        const float* ebase = emb + (size_t)sp * 128 * D_DIM;
        #pragma unroll 4
        for (int it = 0; it < 32; it++) {
            int ch = it * 128 + tid;
            int cc = ((ch >> 9) << 4) | (ch & 15);
            int gg = (ch >> 4) & 31;
            const float* p = ebase + cc * D_DIM + gg * 8;
            float4 v0 = *(const float4*)p;
            float4 v1 = *(const float4*)(p + 4);
            f16x8 h = {(f16)(v0.x * 1024.f), (f16)(v0.y * 1024.f),
                       (f16)(v0.z * 1024.f), (f16)(v0.w * 1024.f),
                       (f16)(v1.x * 1024.f), (f16)(v1.y * 1024.f),
                       (f16)(v1.z * 1024.f), (f16)(v1.w * 1024.f)};
            *(f16x8*)(sE + (size_t)ch * 8) = h;
        }
        __syncthreads();
        for (int ct = 0; ct < 8; ct++) {
            f32x4 acc[4];
            #pragma unroll
            for (int st = 0; st < 4; st++) acc[st] = (f32x4){0.f, 0.f, 0.f, 0.f};
            #pragma unroll
            for (int s = 0; s < 8; s++) {
                f16x8 bh = sE8[ct * 512 + s * 64 + lane];
                #pragma unroll
                for (int st = 0; st < 4; st++)
                    acc[st] = __builtin_amdgcn_mfma_f32_16x16x32_f16(A[st][s], bh, acc[st], 0, 0, 0);
            }
            int codeL = ct * 16 + m;
            float ete = s_ete[codeL];
            int code  = sp * 128 + codeL;
            #pragma unroll
            for (int st = 0; st < 4; st++)
                #pragma unroll
                for (int r = 0; r < 4; r++) {
                    float sc = fmaf(-2.0f, acc[st][r], ete);
                    if (sc < best[st][r]) { best[st][r] = sc; bidx[st][r] = code; }
                }
        }
    }
    #pragma unroll
    for (int st = 0; st < 4; st++)
        #pragma unroll
        for (int r = 0; r < 4; r++) {
            float b = best[st][r]; int bi = bidx[st][r];
            #pragma unroll
            for (int off = 8; off >= 1; off >>= 1) {
                float ob = __shfl_xor(b, off);
                int   oi = __shfl_xor(bi, off);
                if (ob < b || (ob == b && oi < bi)) { b = ob; bi = oi; }
            }
            if (m == 0) s_idx2[wave * 64 + st * 16 + q * 4 + r] = bi;
        }
    __syncthreads();
    float lsum = 0.f;
    #pragma unroll
    for (int st = 0; st < 4; st++) {
        int rl = wave * 64 + st * 16 + m;
        int idxv = s_idx2[rl];
        const float* er = emb + (size_t)idxv * D_DIM;
        float* orow = out + ((size_t)blockIdx.x * 128 + rl) * D_DIM;
        #pragma unroll
        for (int s = 0; s < 8; s++) {
            int dd = s * 32 + q * 8;
            float4 e0 = *(const float4*)(er + dd);
            float4 e1 = *(const float4*)(er + dd + 4);
            *(float4*)(orow + dd)     = e0;
            *(float4*)(orow + dd + 4) = e1;
            f16x8 a = A[st][s];
            float d0 = e0.x - (float)a[0], d1 = e0.y - (float)a[1];
            float d2 = e0.z - (float)a[2], d3 = e0.w - (float)a[3];
            float d4 = e1.x - (float)a[4], d5 = e1.y - (float)a[5];
            float d6 = e1.z - (float)a[6], d7 = e1.w - (float)a[7];
            lsum += d0*d0 + d1*d1 + d2*d2 + d3*d3 + d4*d4 + d5*d5 + d6*d6 + d7*d7;
        }
    }
    #pragma unroll
    for (int off = 32; off >= 1; off >>= 1) lsum += __shfl_down(lsum, off);
    if (lane == 0) s_red2[wave] = lsum;
    __syncthreads();
    if (tid == 0) atomicAdd(loss_slot, (s_red2[0] + s_red2[1]) * loss_scale);
}

extern "C" void kernel_launch(void* const* d_in, const int* in_sizes, int n_in,
                              void* d_out, int out_size, void* d_ws, size_t ws_size,
                              hipStream_t stream) {
    const float* z   = (const float*)d_in[0];
    const float* emb = (const float*)d_in[1];
    float* out = (float*)d_out;
    const int NROWS = in_sizes[0] / D_DIM;                  // 32768
    float* loss_slot = out + (size_t)in_sizes[0];
    float loss_scale = 1.25f / (float)in_sizes[0];

    const size_t emb8_bytes = (size_t)K_CODES * D_DIM;      // 256 KB
    const size_t ete_bytes  = K_CODES * sizeof(float);      // 4 KB
    const size_t need = emb8_bytes + ete_bytes;

    if (ws_size >= need) {
        char*  emb8 = (char*)d_ws;
        float* eTe  = (float*)((char*)d_ws + emb8_bytes);
        vq_prep<<<256, 256, 0, stream>>>(emb, emb8, eTe, loss_slot);
        vq_main7<<<NROWS / 128, 512, 0, stream>>>(z, emb8, eTe, emb, out, loss_slot, loss_scale);
    } else {
        float* eTe = (ws_size >= ete_bytes) ? (float*)d_ws : nullptr;
        vq_prep_fb<<<K_CODES / 4, 256, 0, stream>>>(emb, eTe, loss_slot);
        vq_main_fb<<<NROWS / 128, 128, 0, stream>>>(z, emb, eTe, out, loss_slot, loss_scale);
    }
}